// Round 6
// baseline (136.955 us; speedup 1.0000x reference)
//
#include <hip/hip_runtime.h>
#include <stdint.h>

// B=256, T=512, f32 tensors. v6: prep kernel pre-swizzles bf16 fragment images
// into d_ws. Main kernel: B1 (K=224 incl. one-hots+bias) in VGPRs, B2 in LDS,
// conv computed in A-fragment layout, per-tile y/idx loads double-buffered in
// registers (2-slot pipeline). One __syncthreads (B2 staging).
#define NTOK (256 * 512)
#define TPB 256

typedef short bf16x8 __attribute__((ext_vector_type(8)));
typedef float f32x4 __attribute__((ext_vector_type(4)));
typedef unsigned short u16;
typedef unsigned int u32;

#define B1_U16 10752   // 28 chunks * 48 cols * 8
#define B2_U16 6144    // 8 chunks * 96 cols * 8

__device__ __forceinline__ u16 f2bf(float f) {
    u32 u = __float_as_uint(f);
    return (u16)((u + 0x7fffu + ((u >> 16) & 1u)) >> 16);  // rne
}

// ---------------- prep: build fragment-ordered bf16 weight images ----------------
__global__ __launch_bounds__(256, 1)
void prep_weights(const float* __restrict__ Wxh, const float* __restrict__ bxh,
                  const float* __restrict__ Wwh, const float* __restrict__ bwh,
                  const float* __restrict__ Wyh, const float* __restrict__ byh,
                  const float* __restrict__ Whl, const float* __restrict__ bhl,
                  u16* __restrict__ ws)
{
    int e = blockIdx.x * 256 + threadIdx.x;
    if (e < B1_U16) {
        int j = e & 7, n = (e >> 3) % 48, kc = e / 384;
        int k = kc * 8 + j;                  // k = 2*d + ch for k<176
        float v;
        if (k < 176)       v = Wyh[n * 176 + (k & 1) * 88 + (k >> 1)];
        else if (k < 192)  v = Wxh[n * 16 + (k - 176)];   // x-onehot rows
        else if (k < 208)  v = Wwh[n * 16 + (k - 192)];   // w-onehot rows
        else if (k == 208) v = bxh[n] + bwh[n] + byh[n];  // bias row
        else               v = 0.0f;
        ws[e] = f2bf(v);
    } else if (e < B1_U16 + B2_U16) {
        int e2 = e - B1_U16;
        int j = e2 & 7, dd = (e2 >> 3) % 96, kc = e2 / 768;
        int k = kc * 8 + j;
        float v = 0.0f;
        if (dd < 88) {
            if (k < 48)       v = Whl[dd * 48 + k];
            else if (k == 48) v = bhl[dd];
        }
        ws[e] = f2bf(v);
    }
}

struct Tile { float4 v[6]; int xv, wv; };

// ---------------- main ----------------
__global__ __launch_bounds__(256, 2)
void tones_v6(const int* __restrict__ widx, const int* __restrict__ xidx,
              const float* __restrict__ y,
              const float* __restrict__ Wconv, const float* __restrict__ bconv,
              const u16* __restrict__ wsb,
              float* __restrict__ out)
{
    __shared__ __align__(16) u16 sB2[B2_U16];    // 12,288 B
    __shared__ __align__(16) u16 sH[4 * 1024];   // per-wave H area, 2 KB each

    const int tid = threadIdx.x;
    const int wave = tid >> 6, lane = tid & 63;
    const int q = lane >> 4, c = lane & 15;

    // ---- stage B2 image into LDS (straight uint4 copy, coalesced) ----
    {
        const uint4* src = (const uint4*)(wsb + B1_U16);
        uint4* dst = (uint4*)sB2;
        #pragma unroll
        for (int i = 0; i < 3; i++) dst[tid + 256 * i] = src[tid + 256 * i];
    }

    // ---- B1 fragments into registers (L2-resident pre-swizzled image) ----
    bf16x8 B1[7][3];
    #pragma unroll
    for (int ks = 0; ks < 7; ks++)
        #pragma unroll
        for (int nt = 0; nt < 3; nt++)
            B1[ks][nt] = *(const bf16x8*)(wsb + ((ks * 4 + q) * 48 + nt * 16 + c) * 8);

    const float wc00 = Wconv[0], wc01 = Wconv[1], wc02 = Wconv[2];
    const float wc10 = Wconv[3], wc11 = Wconv[4], wc12 = Wconv[5];
    const float bc0 = bconv[0], bc1 = bconv[1];
    __syncthreads();

    u16* sW = sH + wave * 1024;
    // invariant GEMM2 A chunks: 6 = bias one at k2=48 (j==0), 7 = zeros
    if (lane < 32) {
        uint4 hz = make_uint4((lane < 16) ? 0x3F80u : 0u, 0, 0, 0);
        *(uint4*)(sW + ((6 + (lane >> 4)) * 16 + (lane & 15)) * 8) = hz;
    }

    const int base = blockIdx.x * 256 + wave * 64;

    auto load_tile = [&](int t, Tile& T) {
        const int tb = base + t * 16;
        const float* yc = y + (size_t)(tb + c) * 88;
        #pragma unroll
        for (int s = 0; s < 5; s++)
            T.v[s] = *(const float4*)(yc + 16 * s + 4 * q);
        if (q < 2) T.v[5] = *(const float4*)(yc + 80 + 4 * q);
        else       T.v[5] = make_float4(0.f, 0.f, 0.f, 0.f);
        T.xv = xidx[tb + c];
        T.wv = widx[tb + c];
    };

    auto compute_tile = [&](int t, const Tile& T) {
        const int tb = base + t * 16;
        const float* yc = y + (size_t)(tb + c) * 88;
        f32x4 h0 = {0, 0, 0, 0}, h1 = {0, 0, 0, 0}, h2 = {0, 0, 0, 0};

        // ks=0..4: conv in A-frag layout (d0 = 16s + 4q); p0/p5 are L1 hits
        #pragma unroll
        for (int s = 0; s < 5; s++) {
            const int d0 = 16 * s + 4 * q;
            float p0 = (d0 == 0) ? 0.0f : yc[d0 - 1];
            float p5 = yc[d0 + 4];
            float p[6] = {p0, T.v[s].x, T.v[s].y, T.v[s].z, T.v[s].w, p5};
            bf16x8 af;
            #pragma unroll
            for (int i = 0; i < 4; i++) {
                float c0 = fmaf(wc00, p[i], fmaf(wc01, p[i + 1], fmaf(wc02, p[i + 2], bc0)));
                float c1 = fmaf(wc10, p[i], fmaf(wc11, p[i + 1], fmaf(wc12, p[i + 2], bc1)));
                af[2 * i]     = (short)f2bf(fmaxf(c0, 0.0f));
                af[2 * i + 1] = (short)f2bf(fmaxf(c1, 0.0f));
            }
            h0 = __builtin_amdgcn_mfma_f32_16x16x32_bf16(af, B1[s][0], h0, 0, 0, 0);
            h1 = __builtin_amdgcn_mfma_f32_16x16x32_bf16(af, B1[s][1], h1, 0, 0, 0);
            h2 = __builtin_amdgcn_mfma_f32_16x16x32_bf16(af, B1[s][2], h2, 0, 0, 0);
        }
        // ks=5: q<2 -> conv tail (d0=80,84); q>=2 -> x-onehot dims (q-2)*8+j
        {
            bf16x8 af;
            if (q < 2) {
                const int d0 = 80 + 4 * q;
                float p0 = yc[d0 - 1];
                float p5 = (q == 0) ? yc[84] : 0.0f;
                float p[6] = {p0, T.v[5].x, T.v[5].y, T.v[5].z, T.v[5].w, p5};
                #pragma unroll
                for (int i = 0; i < 4; i++) {
                    float c0 = fmaf(wc00, p[i], fmaf(wc01, p[i + 1], fmaf(wc02, p[i + 2], bc0)));
                    float c1 = fmaf(wc10, p[i], fmaf(wc11, p[i + 1], fmaf(wc12, p[i + 2], bc1)));
                    af[2 * i]     = (short)f2bf(fmaxf(c0, 0.0f));
                    af[2 * i + 1] = (short)f2bf(fmaxf(c1, 0.0f));
                }
            } else {
                const int bse = (q - 2) * 8;
                #pragma unroll
                for (int j = 0; j < 8; j++)
                    af[j] = (short)((bse + j == T.xv) ? 0x3F80 : 0);
            }
            h0 = __builtin_amdgcn_mfma_f32_16x16x32_bf16(af, B1[5][0], h0, 0, 0, 0);
            h1 = __builtin_amdgcn_mfma_f32_16x16x32_bf16(af, B1[5][1], h1, 0, 0, 0);
            h2 = __builtin_amdgcn_mfma_f32_16x16x32_bf16(af, B1[5][2], h2, 0, 0, 0);
        }
        // ks=6: q<2 -> w-onehot dims q*8+j; q==2 -> bias one at j=0; q==3 -> zeros
        {
            bf16x8 af;
            if (q < 2) {
                const int bse = q * 8;
                #pragma unroll
                for (int j = 0; j < 8; j++)
                    af[j] = (short)((bse + j == T.wv) ? 0x3F80 : 0);
            } else {
                #pragma unroll
                for (int j = 0; j < 8; j++)
                    af[j] = (short)((q == 2 && j == 0) ? 0x3F80 : 0);
            }
            h0 = __builtin_amdgcn_mfma_f32_16x16x32_bf16(af, B1[6][0], h0, 0, 0, 0);
            h1 = __builtin_amdgcn_mfma_f32_16x16x32_bf16(af, B1[6][1], h1, 0, 0, 0);
            h2 = __builtin_amdgcn_mfma_f32_16x16x32_bf16(af, B1[6][2], h2, 0, 0, 0);
        }

        // epilogue1: relu -> bf16 H in A-frag layout (chunks 0..5 of sW)
        #pragma unroll
        for (int r = 0; r < 4; r++) {
            const int row = q * 4 + r;
            sW[((0 + (c >> 3)) * 16 + row) * 8 + (c & 7)] = f2bf(fmaxf(h0[r], 0.0f));
            sW[((2 + (c >> 3)) * 16 + row) * 8 + (c & 7)] = f2bf(fmaxf(h1[r], 0.0f));
            sW[((4 + (c >> 3)) * 16 + row) * 8 + (c & 7)] = f2bf(fmaxf(h2[r], 0.0f));
        }

        // GEMM2: out[16x88] = H[16x64] * B2[64x96]
        f32x4 o0 = {0,0,0,0}, o1 = {0,0,0,0}, o2 = {0,0,0,0};
        f32x4 o3 = {0,0,0,0}, o4 = {0,0,0,0}, o5 = {0,0,0,0};
        #pragma unroll
        for (int ks = 0; ks < 2; ks++) {
            bf16x8 a2 = *(const bf16x8*)(sW + ((ks * 4 + q) * 16 + c) * 8);
            bf16x8 b;
            b = *(const bf16x8*)(sB2 + ((ks * 4 + q) * 96 +  0 + c) * 8);
            o0 = __builtin_amdgcn_mfma_f32_16x16x32_bf16(a2, b, o0, 0, 0, 0);
            b = *(const bf16x8*)(sB2 + ((ks * 4 + q) * 96 + 16 + c) * 8);
            o1 = __builtin_amdgcn_mfma_f32_16x16x32_bf16(a2, b, o1, 0, 0, 0);
            b = *(const bf16x8*)(sB2 + ((ks * 4 + q) * 96 + 32 + c) * 8);
            o2 = __builtin_amdgcn_mfma_f32_16x16x32_bf16(a2, b, o2, 0, 0, 0);
            b = *(const bf16x8*)(sB2 + ((ks * 4 + q) * 96 + 48 + c) * 8);
            o3 = __builtin_amdgcn_mfma_f32_16x16x32_bf16(a2, b, o3, 0, 0, 0);
            b = *(const bf16x8*)(sB2 + ((ks * 4 + q) * 96 + 64 + c) * 8);
            o4 = __builtin_amdgcn_mfma_f32_16x16x32_bf16(a2, b, o4, 0, 0, 0);
            b = *(const bf16x8*)(sB2 + ((ks * 4 + q) * 96 + 80 + c) * 8);
            o5 = __builtin_amdgcn_mfma_f32_16x16x32_bf16(a2, b, o5, 0, 0, 0);
        }

        // store: D row = token (q*4+r), col d = nt*16 + c
        float* orow = out + (size_t)(tb + q * 4) * 88;
        #pragma unroll
        for (int r = 0; r < 4; r++) {
            orow[r * 88 +  0 + c] = o0[r];
            orow[r * 88 + 16 + c] = o1[r];
            orow[r * 88 + 32 + c] = o2[r];
            orow[r * 88 + 48 + c] = o3[r];
            orow[r * 88 + 64 + c] = o4[r];
            if (c < 8) orow[r * 88 + 80 + c] = o5[r];
        }
    };

    // ---- 2-slot software pipeline over the 4 tiles ----
    Tile TA, TB;
    load_tile(0, TA);
    load_tile(1, TB);  compute_tile(0, TA);
    load_tile(2, TA);  compute_tile(1, TB);
    load_tile(3, TB);  compute_tile(2, TA);
    compute_tile(3, TB);
}

extern "C" void kernel_launch(void* const* d_in, const int* in_sizes, int n_in,
                              void* d_out, int out_size, void* d_ws, size_t ws_size,
                              hipStream_t stream) {
    (void)in_sizes; (void)n_in; (void)out_size; (void)ws_size;
    u16* ws = (u16*)d_ws;
    prep_weights<<<dim3(66), dim3(TPB), 0, stream>>>(
        (const float*)d_in[3],  (const float*)d_in[4],
        (const float*)d_in[5],  (const float*)d_in[6],
        (const float*)d_in[7],  (const float*)d_in[8],
        (const float*)d_in[11], (const float*)d_in[12], ws);
    tones_v6<<<dim3(NTOK / 256), dim3(TPB), 0, stream>>>(
        (const int*)d_in[0], (const int*)d_in[1], (const float*)d_in[2],
        (const float*)d_in[9], (const float*)d_in[10], ws, (float*)d_out);
}